// Round 1
// baseline (515.371 us; speedup 1.0000x reference)
//
#include <hip/hip_runtime.h>

#define NT 2000
#define NB 256
#define NF 5
#define NS 500
#define NEG_INF (-1e30f)

// One block per batch element. 512 threads: thread s owns fwd state position s
// (s in 0..500; 501..511 idle but participate in barriers).
// fwd double-buffered in LDS; whole x[:, b, :] (40 KB) staged in LDS so the
// 2000-iteration serial loop does LDS-only traffic.
__global__ __launch_bounds__(512) void ctc_fwd_kernel(
    const float* __restrict__ x,      // (NT, NB, NF)
    const int*   __restrict__ seqs,   // (NB, NS)
    const int*   __restrict__ seqlens,// (NB,)
    float*       __restrict__ out)    // (NB,)
{
    __shared__ float xlds[NT * NF];          // 40000 B
    __shared__ float fwd[2][NS + 3];         // 2 x 503 floats, double buffer

    const int b   = blockIdx.x;
    const int tid = threadIdx.x;

    // Stage x[:, b, :] -> LDS (10000 floats). Addresses: t*NB*NF + b*NF + f.
    for (int i = tid; i < NT * NF; i += 512) {
        const int t = i / NF;
        const int f = i - t * NF;
        xlds[i] = x[t * (NB * NF) + b * NF + f];
    }

    // Init fwd[0]: position 0 = 0, rest = -1e30.
    if (tid <= NS) fwd[0][tid] = (tid == 0) ? 0.0f : NEG_INF;

    // t-invariant move index: new[s] (s>=1) uses xt[seqs[b][s-1]].
    int move_idx = 0;
    if (tid >= 1 && tid <= NS) move_idx = seqs[b * NS + (tid - 1)];

    __syncthreads();

    const int s = tid;
    for (int t = 0; t < NT; ++t) {
        const int cur = t & 1;
        const int nxt = cur ^ 1;
        if (s <= NS) {
            const float stay = xlds[t * NF + 4];
            float res = fwd[cur][s] + stay;              // stay transition
            if (s >= 1) {
                const float mv = xlds[t * NF + move_idx] + fwd[cur][s - 1];
                const float m  = fmaxf(mv, res);
                const float d  = fabsf(mv - res);
                res = m + __logf(1.0f + __expf(-d));     // logaddexp
            }
            fwd[nxt][s] = res;
        }
        __syncthreads();   // one barrier per step (double buffer makes it safe)
    }

    // Final state is in buffer (NT & 1) == 0.
    if (tid == 0) {
        const int sl = seqlens[b];
        out[b] = -fwd[0][sl] * (1.0f / (float)NT);
    }
}

extern "C" void kernel_launch(void* const* d_in, const int* in_sizes, int n_in,
                              void* d_out, int out_size, void* d_ws, size_t ws_size,
                              hipStream_t stream) {
    const float* x       = (const float*)d_in[0];
    const int*   seqs    = (const int*)d_in[1];
    const int*   seqlens = (const int*)d_in[2];
    float*       out     = (float*)d_out;

    ctc_fwd_kernel<<<dim3(NB), dim3(512), 0, stream>>>(x, seqs, seqlens, out);
}

// Round 3
// 166.684 us; speedup vs baseline: 3.0919x; 3.0919x over previous
//
#include <hip/hip_runtime.h>

#define NT 2000
#define NB 256
#define NF 5
#define NS 500
#define LOG0   (-1e30f)
#define LOG2E  1.44269504088896340736f
#define LN2F   0.69314718055994530942f
#define RSTRIDE 2024   // wtabT row stride: >=2000, %4==0 (b128 align), %32==8 (banks disjoint)

// One block per batch. 4 waves; wave w spans states [128w-64, 128w+127]:
// 64 left-halo (recomputed redundantly) + 128 owned. Lane L holds 3 adjacent
// states rel=3L..3L+2. Exp-domain recurrence p[s] += p[s-1]*w_t[idx[s]] with
// PER-LANE log2 scale Lw (within-lane spread is tiny -> no underflow).
// Cross-lane handoff: p0 += shfl_up(p2)*adj*w, adj = 2^(Lw_left-Lw_self),
// constant between renorms. Per-lane renorm every 16 steps; cross-wave
// exchange (log2 domain via LDS Gbuf) every 64 steps rebuilds the halo.
__global__ __launch_bounds__(256) void ctc_fwd_kernel(
    const float* __restrict__ x,        // (NT, NB, NF)
    const int*   __restrict__ seqs,     // (NB, NS)
    const int*   __restrict__ seqlens,  // (NB,)
    float*       __restrict__ out)      // (NB,)
{
    __shared__ __align__(16) float wtabT[4 * RSTRIDE];  // w[i][t] = exp(x_t[i]-x_t[4])
    __shared__ float Gbuf[576];                         // log2-domain exchange, idx = 64+s
    __shared__ float red[256];                          // stay-sum reduction

    const int b    = blockIdx.x;
    const int tid  = threadIdx.x;
    const int wave = tid >> 6;
    const int lane = tid & 63;

    // ---------------- precompute: transposed weights + stay sum ----------------
    float csum = 0.f;
    for (int t = tid; t < NT; t += 256) {
        const float* xp = x + (size_t)t * (NB * NF) + b * NF;
        const float x4 = xp[4];
        wtabT[0 * RSTRIDE + t] = __builtin_amdgcn_exp2f((xp[0] - x4) * LOG2E);
        wtabT[1 * RSTRIDE + t] = __builtin_amdgcn_exp2f((xp[1] - x4) * LOG2E);
        wtabT[2 * RSTRIDE + t] = __builtin_amdgcn_exp2f((xp[2] - x4) * LOG2E);
        wtabT[3 * RSTRIDE + t] = __builtin_amdgcn_exp2f((xp[3] - x4) * LOG2E);
        csum += x4;
    }
    for (int i = tid; i < 576; i += 256) Gbuf[i] = LOG0;
    red[tid] = csum;
    __syncthreads();
    for (int off = 128; off > 0; off >>= 1) {
        if (tid < off) red[tid] += red[tid + off];
        __syncthreads();
    }
    // red[0] = C = sum over t of x_t[4]

    // ---------------- per-lane setup ----------------
    const int wbase = wave * 128 - 64;
    const int rel0 = 3 * lane;
    const int s0 = wbase + rel0, s1 = s0 + 1, s2 = s0 + 2;

    const int i0 = (s0 >= 1 && s0 <= NS) ? seqs[b * NS + s0 - 1] : 0;
    const int i1 = (s1 >= 1 && s1 <= NS) ? seqs[b * NS + s1 - 1] : 0;
    const int i2 = (s2 >= 1 && s2 <= NS) ? seqs[b * NS + s2 - 1] : 0;
    const float* wrow0 = &wtabT[i0 * RSTRIDE];
    const float* wrow1 = &wtabT[i1 * RSTRIDE];
    const float* wrow2 = &wtabT[i2 * RSTRIDE];

    float p0 = (s0 == 0) ? 1.f : 0.f;
    float p1 = (s1 == 0) ? 1.f : 0.f;
    float p2 = (s2 == 0) ? 1.f : 0.f;
    float Lw  = 0.f;   // per-lane log2 offset
    float adj = 1.f;   // 2^(Lw_left - Lw_self), refreshed after every renorm/exchange

#define STEP(W0, W1, W2) do {                 \
        const float sh = __shfl_up(p2, 1);    \
        p2 = fmaf(p1, (W2), p2);              \
        p1 = fmaf(p0, (W1), p1);              \
        p0 = fmaf(sh * adj, (W0), p0);        \
    } while (0)

    // ---------------- main loop: 125 chunks of 16 steps ----------------
    for (int c = 0; c < 125; ++c) {
        if (c > 0) {
            if ((c & 3) == 0) {
                // ---- cross-wave exchange every 64 steps (log2 domain) ----
                __syncthreads();
                if (rel0     >= 64) Gbuf[64 + s0] = (p0 > 0.f) ? __builtin_amdgcn_logf(p0) + Lw : LOG0;
                if (rel0 + 1 >= 64) Gbuf[64 + s1] = (p1 > 0.f) ? __builtin_amdgcn_logf(p1) + Lw : LOG0;
                if (rel0 + 2 >= 64) Gbuf[64 + s2] = (p2 > 0.f) ? __builtin_amdgcn_logf(p2) + Lw : LOG0;
                __syncthreads();
                const float g0 = Gbuf[64 + s0];
                const float g1 = Gbuf[64 + s1];
                const float g2 = Gbuf[64 + s2];
                const float ref = fmaxf(fmaxf(g0, g1), g2);
                const bool alive = (ref > 0.5f * LOG0);
                // live states form a prefix of the window -> last live lane is
                // nearest-live-left for all dead lanes
                int lastlive = alive ? lane : -1;
                #pragma unroll
                for (int o = 1; o < 64; o <<= 1) lastlive = max(lastlive, __shfl_xor(lastlive, o));
                float fb = __shfl(ref, (lastlive >= 0) ? lastlive : 0);
                if (lastlive < 0) fb = 0.f;
                Lw = alive ? ref : fb;
                p0 = __builtin_amdgcn_exp2f(g0 - Lw);   // dead: exp2(-1e30)=0
                p1 = __builtin_amdgcn_exp2f(g1 - Lw);
                p2 = __builtin_amdgcn_exp2f(g2 - Lw);
            } else {
                // ---- per-lane renorm every 16 steps ----
                const float m = fmaxf(fmaxf(p0, p1), p2);
                if (m > 0.f) {
                    const float inv = __builtin_amdgcn_rcpf(m);
                    Lw += __builtin_amdgcn_logf(m);     // v_log_f32 = log2
                    p0 *= inv; p1 *= inv; p2 *= inv;
                }
            }
            const float Lwp = __shfl_up(Lw, 1);
            adj = __builtin_amdgcn_exp2f(fminf(Lwp - Lw, 100.f));
        }
        const int tb = c << 4;
        #pragma unroll
        for (int q = 0; q < 4; ++q) {
            const float4 wa = *reinterpret_cast<const float4*>(wrow0 + tb + 4 * q);
            const float4 wb = *reinterpret_cast<const float4*>(wrow1 + tb + 4 * q);
            const float4 wc = *reinterpret_cast<const float4*>(wrow2 + tb + 4 * q);
            STEP(wa.x, wb.x, wc.x);
            STEP(wa.y, wb.y, wc.y);
            STEP(wa.z, wb.z, wc.z);
            STEP(wa.w, wb.w, wc.w);
        }
    }
#undef STEP

    // ---------------- final write-out ----------------
    __syncthreads();
    if (rel0     >= 64) Gbuf[64 + s0] = (p0 > 0.f) ? __builtin_amdgcn_logf(p0) + Lw : LOG0;
    if (rel0 + 1 >= 64) Gbuf[64 + s1] = (p1 > 0.f) ? __builtin_amdgcn_logf(p1) + Lw : LOG0;
    if (rel0 + 2 >= 64) Gbuf[64 + s2] = (p2 > 0.f) ? __builtin_amdgcn_logf(p2) + Lw : LOG0;
    __syncthreads();
    if (tid == 0) {
        const int sl = seqlens[b];
        out[b] = -(Gbuf[64 + sl] * LN2F + red[0]) * (1.0f / (float)NT);
    }
}

extern "C" void kernel_launch(void* const* d_in, const int* in_sizes, int n_in,
                              void* d_out, int out_size, void* d_ws, size_t ws_size,
                              hipStream_t stream) {
    const float* x       = (const float*)d_in[0];
    const int*   seqs    = (const int*)d_in[1];
    const int*   seqlens = (const int*)d_in[2];
    float*       out     = (float*)d_out;

    ctc_fwd_kernel<<<dim3(NB), dim3(256), 0, stream>>>(x, seqs, seqlens, out);
}